// Round 5
// baseline (365305.396 us; speedup 1.0000x reference)
//
#include <hip/hip_runtime.h>

// Problem constants
#define T_   512
#define B_   64
#define V_   256
#define E_   256
#define H_   512
#define NWGD 32           // workgroups per direction
#define THR  256

typedef _Float16 f16;
typedef _Float16 f16x8 __attribute__((ext_vector_type(8)));
typedef _Float16 f16x4 __attribute__((ext_vector_type(4)));
typedef float    f32x4 __attribute__((ext_vector_type(4)));

// ---------------- workspace layout (bytes) ----------------
// ctl ints: claim[xcd] at int ofs xcd*16; flags dir0 at int ofs 64 (stride 16),
// dir1 at int ofs 576.
#define WS_CTL      0
#define WS_CTL_END  8192
#define WS_SCORES   WS_CTL_END                          // T*B f32
#define WS_ATTN     (WS_SCORES + 512*64*4)              // T*B f32
#define WS_ZERO_END (WS_ATTN + 512*64*4)
#define WS_TAB      WS_ZERO_END                         // embed table f16 256*256
#define WS_WARR     (WS_TAB + 256*256*2)                // 2*2048*768 f16
#define WS_WWT      (WS_WARR + 2*2048*768*2)            // W_W^T f16 1024*1024
#define WS_HBUF     (WS_WWT + 1024*1024*2)              // 2 buf * 2 dir * 64*512 f16
#define WS_OUT      (WS_HBUF + 2*2*64*512*2)            // out_cat f16 512*64*1024
#define WS_END      (WS_OUT + (size_t)512*64*1024*2)

// ---------------- asm helpers ----------------
__device__ inline int xcc_id() {
    int x;
    asm volatile("s_getreg_b32 %0, hwreg(HW_REG_XCC_ID)" : "=s"(x));
    return x & 7;
}

// L2-scope (XCD-local) poll: bypass L1, hit shared L2
__device__ inline int load_int_sc0(const int* p) {
    int v;
    asm volatile("global_load_dword %0, %1, off sc0\n\ts_waitcnt vmcnt(0)"
                 : "=v"(v) : "v"(p) : "memory");
    return v;
}

__device__ inline void store_int_plain(int* p, int v) {
    asm volatile("global_store_dword %0, %1, off"
                 :: "v"(p), "v"(v) : "memory");
}

__device__ inline void drain_vm() {
    asm volatile("s_waitcnt vmcnt(0)" ::: "memory");
}

// nowait vector-load issues; OFFB must be a literal token (byte offset)
#define LD4(dst, base, OFFB) \
    asm volatile("global_load_dwordx4 %0, %1, off offset:" #OFFB \
                 : "=v"(dst) : "v"(base))
#define LD4C(dst, base, OFFB) \
    asm volatile("global_load_dwordx4 %0, %1, off offset:" #OFFB " sc0" \
                 : "=v"(dst) : "v"(base))
#define WAITVM(N) do { \
    asm volatile("s_waitcnt vmcnt(" #N ")" ::: "memory"); \
    __builtin_amdgcn_sched_barrier(0); } while (0)

__device__ inline float fast_sigmoid(float x) {
    return 1.f / (1.f + __expf(-x));
}
__device__ inline float fast_tanh(float x) {
    float e = __expf(-2.f * x);
    return 2.f / (1.f + e) - 1.f;     // exact limits at +/-inf, no NaN
}

// ---------------- setup kernels ----------------
__global__ void k_setup_table(const float* __restrict__ et, f16* __restrict__ tab) {
    int i = blockIdx.x * 256 + threadIdx.x;   // 65536
    tab[i] = (f16)et[i];
}

__global__ void k_setup_wwt(const float* __restrict__ ww, f16* __restrict__ wwt) {
    int i = blockIdx.x * 256 + threadIdx.x;   // 1048576
    int col = i >> 10, h = i & 1023;
    wwt[(col << 10) + h] = (f16)ww[(h << 10) + col];   // store [col][h]
}

__global__ void k_setup_warr(const float* __restrict__ wihf, const float* __restrict__ whhf,
                             const float* __restrict__ wihb, const float* __restrict__ whhb,
                             f16* __restrict__ warr) {
    int i = blockIdx.x * 256 + threadIdx.x;   // 3145728
    int k = i % 768;
    int r = i / 768;                          // (dir*32+wg)*64 + col'
    int colp = r & 63;
    int wg   = (r >> 6) & 31;
    int dir  = r >> 11;
    int gate = colp >> 4, u = colp & 15;
    int row = gate * 512 + wg * 16 + u;
    const float* wih = dir ? wihb : wihf;
    const float* whh = dir ? whhb : whhf;
    float v = (k < 256) ? wih[row * 256 + k] : whh[row * 512 + (k - 256)];
    warr[i] = (f16)v;
}

// ---------------- persistent bidirectional LSTM (XCD-local sync) ----------------
// 256 blocks x 256 thr, 84KB dyn LDS -> exactly 1 block/CU -> all co-resident,
// 32 blocks/XCD. XCD 0 = dir 0, XCD 1 = dir 1, others exit. h + flags stay in
// the XCD's L2 (plain stores, sc0 loads). A-frags load directly from global.
#define GSTR 68   // gate LDS row stride (f32)
#define LDS_ALLOC 86016   // 84 KB: 2 blocks would need 168KB > 160KB -> exclusive

__launch_bounds__(THR, 1)
__global__ void k_lstm(const int* __restrict__ tokens,
                       const float* __restrict__ h0, const float* __restrict__ c0,
                       const float* __restrict__ b_f, const float* __restrict__ b_b,
                       const f16* __restrict__ tab, const f16* __restrict__ warr,
                       f16* __restrict__ hbuf, f16* __restrict__ outcat,
                       int* __restrict__ ctl) {
    extern __shared__ __align__(16) char smem[];
    float* gate = (float*)smem;                         // 64*GSTR f32 = 17408 B
    float* cst  = (float*)(smem + 64 * GSTR * 4);       // 64*16 f32  =  4096 B
    __shared__ int sb_info[2];

    const int tid = threadIdx.x;

    // ---- claim an XCD-local slot (device-scope atomic at MALL) ----
    if (tid == 0) {
        int xcc = xcc_id();
        int slot = atomicAdd(ctl + xcc * 16, 1);
        sb_info[0] = xcc; sb_info[1] = slot;
    }
    __syncthreads();
    const int xcc = sb_info[0], slot = sb_info[1];
    if (xcc >= 2 || slot >= NWGD) return;   // non-member: free the CU
    const int dir = xcc, wg = slot;

    int* flags = ctl + 64 + dir * 512;      // [wg] stride 16 ints (64 B)

    const int l = tid & 63, w = tid >> 6;
    const int mh = w >> 1, nh = w & 1;
    const int r0 = mh * 32 + (l & 15), r1 = r0 + 16;   // A rows (batch)
    const int kofs = (l >> 4) * 8;                     // lane's k sub-offset (f16)

    // ---- preload weights into registers (B fragments) ----
    f16x8 bf0[24], bf1[24];
#pragma unroll
    for (int kt = 0; kt < 24; ++kt) {
        int colp0 = nh * 32 + 0 * 16 + (l & 15);
        int colp1 = nh * 32 + 1 * 16 + (l & 15);
        long base = (long)((dir * 32 + wg) * 64) * 768;
        bf0[kt] = *(const f16x8*)(warr + base + (long)colp0 * 768 + kt * 32 + kofs);
        bf1[kt] = *(const f16x8*)(warr + base + (long)colp1 * 768 + kt * 32 + kofs);
    }

    // ---- epilogue mapping: thread owns (pb, u0..u0+3) ----
    const int pb = tid >> 2;
    const int u0 = (tid & 3) * 4;
    const float* bv = dir ? b_b : b_f;
    f32x4 bias[4];
#pragma unroll
    for (int g = 0; g < 4; ++g)
        bias[g] = *(const f32x4*)(bv + g * 512 + wg * 16 + u0);

    // ---- init c (LDS f32) and h (hbuf parity 0, plain -> this XCD's L2) ----
    {
        f32x4 cv = *(const f32x4*)(c0 + (dir * 64 + pb) * 512 + wg * 16 + u0);
        *(f32x4*)(cst + pb * 16 + u0) = cv;
        f32x4 h4 = *(const f32x4*)(h0 + (dir * 64 + pb) * 512 + wg * 16 + u0);
        f16x4 hv;
#pragma unroll
        for (int j = 0; j < 4; ++j) hv[j] = (f16)h4[j];
        *(f16x4*)(hbuf + ((0 * 2 + dir) * 64 + pb) * 512 + wg * 16 + u0) = hv;
    }
    drain_vm();
    __syncthreads();
    if (tid == 0) store_int_plain(flags + wg * 16, 1);

    // tokens for step 0
    int tok0 = tokens[(dir ? 511 : 0) * 64 + r0];
    int tok1 = tokens[(dir ? 511 : 0) * 64 + r1];

#pragma unroll 1
    for (int s = 0; s < 512; ++s) {
        const int t_act = dir ? (511 - s) : s;

        // ---- issue emb A-frag loads (pre-poll; latency hides under poll) ----
        f16x8 e0[8], e1[8];
        {
            const f16* p0 = tab + tok0 * 256 + kofs;
            const f16* p1 = tab + tok1 * 256 + kofs;
            LD4(e0[0], p0, 0);   LD4(e1[0], p1, 0);
            LD4(e0[1], p0, 64);  LD4(e1[1], p1, 64);
            LD4(e0[2], p0, 128); LD4(e1[2], p1, 128);
            LD4(e0[3], p0, 192); LD4(e1[3], p1, 192);
            LD4(e0[4], p0, 256); LD4(e1[4], p1, 256);
            LD4(e0[5], p0, 320); LD4(e1[5], p1, 320);
            LD4(e0[6], p0, 384); LD4(e1[6], p1, 384);
            LD4(e0[7], p0, 448); LD4(e1[7], p1, 448);
        }

        // ---- wait for all 32 h-slices of version s (flag >= s+1), L2 scope ----
        {
            const int* fp = flags + (l & 31) * 16;
            const int target = s + 1;
            int guard = 0;
            while (true) {
                int v = load_int_sc0(fp);   // internal vmcnt(0) also retires emb
                if (__all(v >= target)) break;
                if (++guard > 8192) break;  // bounded: fail fast, never hang
            }
        }
        __builtin_amdgcn_sched_barrier(0);  // keep h loads/MFMAs below the poll

        // ---- issue first-half h A-frags (k-tiles 8..15) from XCD L2 ----
        const f16* hbase = hbuf + (long)(((s & 1) * 2 + dir) * 64) * 512;
        const f16* pr0 = hbase + r0 * 512 + kofs;
        const f16* pr1 = hbase + r1 * 512 + kofs;
        f16x8 ha0[8], ha1[8], hc0[8], hc1[8];
        LD4C(ha0[0], pr0, 0);   LD4C(ha1[0], pr1, 0);
        LD4C(ha0[1], pr0, 64);  LD4C(ha1[1], pr1, 64);
        LD4C(ha0[2], pr0, 128); LD4C(ha1[2], pr1, 128);
        LD4C(ha0[3], pr0, 192); LD4C(ha1[3], pr1, 192);
        LD4C(ha0[4], pr0, 256); LD4C(ha1[4], pr1, 256);
        LD4C(ha0[5], pr0, 320); LD4C(ha1[5], pr1, 320);
        LD4C(ha0[6], pr0, 384); LD4C(ha1[6], pr1, 384);
        LD4C(ha0[7], pr0, 448); LD4C(ha1[7], pr1, 448);

        // ---- emb MFMAs (k-tiles 0..7) ----
        f32x4 a00 = {0.f,0.f,0.f,0.f}, a01 = {0.f,0.f,0.f,0.f};
        f32x4 a10 = {0.f,0.f,0.f,0.f}, a11 = {0.f,0.f,0.f,0.f};
#pragma unroll
        for (int kt = 0; kt < 8; ++kt) {
            a00 = __builtin_amdgcn_mfma_f32_16x16x32_f16(e0[kt], bf0[kt], a00, 0, 0, 0);
            a01 = __builtin_amdgcn_mfma_f32_16x16x32_f16(e0[kt], bf1[kt], a01, 0, 0, 0);
            a10 = __builtin_amdgcn_mfma_f32_16x16x32_f16(e1[kt], bf0[kt], a10, 0, 0, 0);
            a11 = __builtin_amdgcn_mfma_f32_16x16x32_f16(e1[kt], bf1[kt], a11, 0, 0, 0);
        }

        // ---- issue second-half h A-frags (k-tiles 16..23) ----
        LD4C(hc0[0], pr0, 512); LD4C(hc1[0], pr1, 512);
        LD4C(hc0[1], pr0, 576); LD4C(hc1[1], pr1, 576);
        LD4C(hc0[2], pr0, 640); LD4C(hc1[2], pr1, 640);
        LD4C(hc0[3], pr0, 704); LD4C(hc1[3], pr1, 704);
        LD4C(hc0[4], pr0, 768); LD4C(hc1[4], pr1, 768);
        LD4C(hc0[5], pr0, 832); LD4C(hc1[5], pr1, 832);
        LD4C(hc0[6], pr0, 896); LD4C(hc1[6], pr1, 896);
        LD4C(hc0[7], pr0, 960); LD4C(hc1[7], pr1, 960);

        WAITVM(16);   // first-half h frags retired (second half is newest 16)
#pragma unroll
        for (int kt = 0; kt < 8; ++kt) {
            a00 = __builtin_amdgcn_mfma_f32_16x16x32_f16(ha0[kt], bf0[kt + 8], a00, 0, 0, 0);
            a01 = __builtin_amdgcn_mfma_f32_16x16x32_f16(ha0[kt], bf1[kt + 8], a01, 0, 0, 0);
            a10 = __builtin_amdgcn_mfma_f32_16x16x32_f16(ha1[kt], bf0[kt + 8], a10, 0, 0, 0);
            a11 = __builtin_amdgcn_mfma_f32_16x16x32_f16(ha1[kt], bf1[kt + 8], a11, 0, 0, 0);
        }
        WAITVM(0);    // second-half h frags retired
#pragma unroll
        for (int kt = 0; kt < 8; ++kt) {
            a00 = __builtin_amdgcn_mfma_f32_16x16x32_f16(hc0[kt], bf0[kt + 16], a00, 0, 0, 0);
            a01 = __builtin_amdgcn_mfma_f32_16x16x32_f16(hc0[kt], bf1[kt + 16], a01, 0, 0, 0);
            a10 = __builtin_amdgcn_mfma_f32_16x16x32_f16(hc1[kt], bf0[kt + 16], a10, 0, 0, 0);
            a11 = __builtin_amdgcn_mfma_f32_16x16x32_f16(hc1[kt], bf1[kt + 16], a11, 0, 0, 0);
        }

        // ---- write gates to LDS ----
#pragma unroll
        for (int q = 0; q < 4; ++q) {
            int br0 = mh * 32 + (l >> 4) * 4 + q;
            int br1 = br0 + 16;
            int cl0 = nh * 32 + (l & 15);
            gate[br0 * GSTR + cl0]      = a00[q];
            gate[br0 * GSTR + cl0 + 16] = a01[q];
            gate[br1 * GSTR + cl0]      = a10[q];
            gate[br1 * GSTR + cl0 + 16] = a11[q];
        }
        __syncthreads();

        // ---- epilogue: tokens for s+1, nonlinearity, c/h update ----
        {
            int sn = (s < 511) ? (s + 1) : 511;
            int tn = dir ? (511 - sn) : sn;
            tok0 = tokens[tn * 64 + r0];
            tok1 = tokens[tn * 64 + r1];
        }
        f16x4 hv;
        {
            f32x4 g0 = *(const f32x4*)(gate + pb * GSTR +  0 + u0);
            f32x4 g1 = *(const f32x4*)(gate + pb * GSTR + 16 + u0);
            f32x4 g2 = *(const f32x4*)(gate + pb * GSTR + 32 + u0);
            f32x4 g3 = *(const f32x4*)(gate + pb * GSTR + 48 + u0);
            f32x4 cv = *(const f32x4*)(cst + pb * 16 + u0);
#pragma unroll
            for (int j = 0; j < 4; ++j) {
                float si = fast_sigmoid(g0[j] + bias[0][j]);
                float sf = fast_sigmoid(g1[j] + bias[1][j]);
                float tg = fast_tanh(g2[j] + bias[2][j]);
                float so = fast_sigmoid(g3[j] + bias[3][j]);
                float c = sf * cv[j] + si * tg;
                float h = so * fast_tanh(c);
                cv[j] = c;
                hv[j] = (f16)h;
            }
            *(f32x4*)(cst + pb * 16 + u0) = cv;
            // h store FIRST (plain -> XCD L2), it gates the flag release
            *(f16x4*)(hbuf + ((((s + 1) & 1) * 2 + dir) * 64 + pb) * 512 + wg * 16 + u0) = hv;
        }
        drain_vm();                 // h stores acked at L2
        __syncthreads();
        if (tid == 0) store_int_plain(flags + wg * 16, s + 2);
        // outcat store AFTER flag release: off the critical path
        *(f16x4*)(outcat + ((long)t_act * 64 + pb) * 1024 + dir * 512 + wg * 16 + u0) = hv;
    }
}

// ---------------- attention GEMM: scores += tanh(out@W_W + b) . w_proj ----------------
__global__ void k_attn_gemm(const f16* __restrict__ outcat, const f16* __restrict__ wwt,
                            const float* __restrict__ b_att, const float* __restrict__ w_proj,
                            float* __restrict__ scores) {
    __shared__ __align__(16) f16 A2[64][136];
    __shared__ __align__(16) f16 B2[64][136];
    __shared__ float sq[64][68];
    const int tid = threadIdx.x;
    const int mb = blockIdx.x >> 4, nb = blockIdx.x & 15;
    const int r0 = mb * 64, c0 = nb * 64;
    const int l = tid & 63, w = tid >> 6;
    const int mh = w >> 1, nhf = w & 1;

    f32x4 acc[2][2];
#pragma unroll
    for (int m = 0; m < 2; ++m)
#pragma unroll
        for (int n = 0; n < 2; ++n)
            acc[m][n] = (f32x4){0.f, 0.f, 0.f, 0.f};

    for (int kc = 0; kc < 8; ++kc) {
        int k0 = kc * 128;
        {
            int row = tid >> 2, seg = tid & 3;
            const f16* sa = outcat + (long)(r0 + row) * 1024 + k0 + seg * 32;
            const f16* sb = wwt + (long)(c0 + row) * 1024 + k0 + seg * 32;
#pragma unroll
            for (int j = 0; j < 4; ++j) {
                *(f16x8*)(&A2[row][seg * 32 + j * 8]) = *(const f16x8*)(sa + j * 8);
                *(f16x8*)(&B2[row][seg * 32 + j * 8]) = *(const f16x8*)(sb + j * 8);
            }
        }
        __syncthreads();
        const int kofs = (l >> 4) * 8;
#pragma unroll
        for (int kt = 0; kt < 4; ++kt) {
            int ko = kt * 32 + kofs;
            f16x8 a0 = *(const f16x8*)(&A2[mh * 32 + (l & 15)][ko]);
            f16x8 a1 = *(const f16x8*)(&A2[mh * 32 + 16 + (l & 15)][ko]);
            f16x8 b0 = *(const f16x8*)(&B2[nhf * 32 + (l & 15)][ko]);
            f16x8 b1 = *(const f16x8*)(&B2[nhf * 32 + 16 + (l & 15)][ko]);
            acc[0][0] = __builtin_amdgcn_mfma_f32_16x16x32_f16(a0, b0, acc[0][0], 0, 0, 0);
            acc[0][1] = __builtin_amdgcn_mfma_f32_16x16x32_f16(a0, b1, acc[0][1], 0, 0, 0);
            acc[1][0] = __builtin_amdgcn_mfma_f32_16x16x32_f16(a1, b0, acc[1][0], 0, 0, 0);
            acc[1][1] = __builtin_amdgcn_mfma_f32_16x16x32_f16(a1, b1, acc[1][1], 0, 0, 0);
        }
        __syncthreads();
    }
#pragma unroll
    for (int m = 0; m < 2; ++m)
#pragma unroll
        for (int n = 0; n < 2; ++n)
#pragma unroll
            for (int q = 0; q < 4; ++q) {
                int rl = mh * 32 + m * 16 + (l >> 4) * 4 + q;
                int cl = nhf * 32 + n * 16 + (l & 15);
                int cg = c0 + cl;
                sq[rl][cl] = tanhf(acc[m][n][q] + b_att[cg]) * w_proj[cg];
            }
    __syncthreads();
    if (tid < 64) {
        float s = 0.f;
#pragma unroll
        for (int c2 = 0; c2 < 64; ++c2) s += sq[tid][c2];
        atomicAdd(scores + r0 + tid, s);
    }
}

// ---------------- softmax over T (per batch) ----------------
__global__ void k_softmax(const float* __restrict__ scores, float* __restrict__ attn) {
    const int b = blockIdx.x, tid = threadIdx.x;
    __shared__ float redm[4];
    __shared__ float reds[4];
    float v0 = scores[(tid * 2 + 0) * 64 + b];
    float v1 = scores[(tid * 2 + 1) * 64 + b];
    float m = fmaxf(v0, v1);
#pragma unroll
    for (int off = 32; off; off >>= 1) m = fmaxf(m, __shfl_down(m, off));
    if ((tid & 63) == 0) redm[tid >> 6] = m;
    __syncthreads();
    m = fmaxf(fmaxf(redm[0], redm[1]), fmaxf(redm[2], redm[3]));
    float e0 = __expf(v0 - m), e1 = __expf(v1 - m);
    float s = e0 + e1;
#pragma unroll
    for (int off = 32; off; off >>= 1) s += __shfl_down(s, off);
    if ((tid & 63) == 0) reds[tid >> 6] = s;
    __syncthreads();
    s = (reds[0] + reds[1]) + (reds[2] + reds[3]);
    float inv = 1.f / s;
    attn[(tid * 2 + 0) * 64 + b] = e0 * inv;
    attn[(tid * 2 + 1) * 64 + b] = e1 * inv;
}

// ---------------- weighted sum: char_vectors[b][c] ----------------
__global__ void k_wsum(const float* __restrict__ attn, const f16* __restrict__ outcat,
                       float* __restrict__ out) {
    const int b = blockIdx.x, tid = threadIdx.x;
    float a0 = 0.f, a1 = 0.f, a2 = 0.f, a3 = 0.f;
    for (int t = 0; t < 512; ++t) {
        float at = attn[t * 64 + b];
        f16x4 v = *(const f16x4*)(outcat + ((long)t * 64 + b) * 1024 + tid * 4);
        a0 += at * (float)v[0];
        a1 += at * (float)v[1];
        a2 += at * (float)v[2];
        a3 += at * (float)v[3];
    }
    float* dst = out + b * 1024 + tid * 4;
    dst[0] = a0; dst[1] = a1; dst[2] = a2; dst[3] = a3;
}

// ---------------- launch ----------------
extern "C" void kernel_launch(void* const* d_in, const int* in_sizes, int n_in,
                              void* d_out, int out_size, void* d_ws, size_t ws_size,
                              hipStream_t stream) {
    if (ws_size < WS_END) return;

    const int*   tokens = (const int*)d_in[0];
    const float* h0     = (const float*)d_in[1];
    const float* c0     = (const float*)d_in[2];
    const float* etab   = (const float*)d_in[3];
    const float* wihf   = (const float*)d_in[4];
    const float* whhf   = (const float*)d_in[5];
    const float* b_f    = (const float*)d_in[6];
    const float* wihb   = (const float*)d_in[7];
    const float* whhb   = (const float*)d_in[8];
    const float* b_b    = (const float*)d_in[9];
    const float* ww     = (const float*)d_in[10];
    const float* b_att  = (const float*)d_in[11];
    const float* w_proj = (const float*)d_in[12];
    float* out = (float*)d_out;

    char* ws = (char*)d_ws;
    int*   ctl    = (int*)(ws + WS_CTL);
    float* scores = (float*)(ws + WS_SCORES);
    float* attn   = (float*)(ws + WS_ATTN);
    f16*   tab    = (f16*)(ws + WS_TAB);
    f16*   warr   = (f16*)(ws + WS_WARR);
    f16*   wwt    = (f16*)(ws + WS_WWT);
    f16*   hbuf   = (f16*)(ws + WS_HBUF);
    f16*   outcat = (f16*)(ws + WS_OUT);

    hipMemsetAsync(d_ws, 0, WS_ZERO_END, stream);

    k_setup_table<<<256, 256, 0, stream>>>(etab, tab);
    k_setup_wwt<<<4096, 256, 0, stream>>>(ww, wwt);
    k_setup_warr<<<12288, 256, 0, stream>>>(wihf, whhf, wihb, whhb, warr);

    static int lds_set = 0;
    if (!lds_set) {
        hipFuncSetAttribute((const void*)k_lstm,
                            hipFuncAttributeMaxDynamicSharedMemorySize, LDS_ALLOC);
        lds_set = 1;
    }
    k_lstm<<<256, THR, LDS_ALLOC, stream>>>(tokens, h0, c0, b_f, b_b,
                                            tab, warr, hbuf, outcat, ctl);

    k_attn_gemm<<<8192, 256, 0, stream>>>(outcat, wwt, b_att, w_proj, scores);
    k_softmax<<<64, 256, 0, stream>>>(scores, attn);
    k_wsum<<<64, 256, 0, stream>>>(attn, outcat, out);
}

// Round 6
// 4328.529 us; speedup vs baseline: 84.3948x; 84.3948x over previous
//
#include <hip/hip_runtime.h>

// Problem constants
#define T_   512
#define B_   64
#define V_   256
#define E_   256
#define H_   512
#define NWGD 32           // workgroups per direction
#define THR  256

typedef _Float16 f16;
typedef _Float16 f16x8 __attribute__((ext_vector_type(8)));
typedef _Float16 f16x4 __attribute__((ext_vector_type(4)));
typedef float    f32x4 __attribute__((ext_vector_type(4)));

// ---------------- workspace layout (bytes) ----------------
// ctl ints: flags at int ofs 64 + ((dir*32+wg)*4 + wave)*16   (64B stride)
#define WS_CTL      0
#define WS_CTL_END  20480
#define WS_SCORES   WS_CTL_END                          // T*B f32
#define WS_ATTN     (WS_SCORES + 512*64*4)              // T*B f32
#define WS_ZERO_END (WS_ATTN + 512*64*4)
#define WS_TAB      WS_ZERO_END                         // embed table f16 256*256
#define WS_WARR     (WS_TAB + 256*256*2)                // 2*2048*768 f16
#define WS_WWT      (WS_WARR + 2*2048*768*2)            // W_W^T f16 1024*1024
#define WS_HBUF     (WS_WWT + 1024*1024*2)              // 2 buf * 2 dir * 64*512 f16
#define WS_OUT      (WS_HBUF + 2*2*64*512*2)            // out_cat f16 512*64*1024
#define WS_END      (WS_OUT + (size_t)512*64*1024*2)

// ---------------- asm helpers: device-coherent (MALL) accesses ----------------
__device__ inline int load_int_sc1(const int* p) {
    int v;
    asm volatile("global_load_dword %0, %1, off sc1\n\ts_waitcnt vmcnt(0)"
                 : "=v"(v) : "v"(p) : "memory");
    return v;
}

__device__ inline void store_int_sc1(int* p, int v) {
    asm volatile("global_store_dword %0, %1, off sc1"
                 :: "v"(p), "v"(v) : "memory");
}

__device__ inline void store_f16x4_sc1(f16* p, f16x4 v) {
    asm volatile("global_store_dwordx2 %0, %1, off sc1"
                 :: "v"(p), "v"(v) : "memory");
}

__device__ inline void drain_vm() {
    asm volatile("s_waitcnt vmcnt(0)" ::: "memory");
}

// nowait vector-load issues; OFFB must be a literal token (byte offset)
#define LD4(dst, base, OFFB) \
    asm volatile("global_load_dwordx4 %0, %1, off offset:" #OFFB \
                 : "=v"(dst) : "v"(base))
#define LD4S(dst, base, OFFB) \
    asm volatile("global_load_dwordx4 %0, %1, off offset:" #OFFB " sc1" \
                 : "=v"(dst) : "v"(base))
#define WAITVM(N) do { \
    asm volatile("s_waitcnt vmcnt(" #N ")" ::: "memory"); \
    __builtin_amdgcn_sched_barrier(0); } while (0)

__device__ inline float fast_sigmoid(float x) {
    return 1.f / (1.f + __expf(-x));
}
__device__ inline float fast_tanh(float x) {
    float e = __expf(-2.f * x);
    return 2.f / (1.f + e) - 1.f;     // exact limits at +/-inf, no NaN
}

// ---------------- setup kernels ----------------
__global__ void k_setup_table(const float* __restrict__ et, f16* __restrict__ tab) {
    int i = blockIdx.x * 256 + threadIdx.x;   // 65536
    tab[i] = (f16)et[i];
}

__global__ void k_setup_wwt(const float* __restrict__ ww, f16* __restrict__ wwt) {
    int i = blockIdx.x * 256 + threadIdx.x;   // 1048576
    int col = i >> 10, h = i & 1023;
    wwt[(col << 10) + h] = (f16)ww[(h << 10) + col];   // store [col][h]
}

__global__ void k_setup_warr(const float* __restrict__ wihf, const float* __restrict__ whhf,
                             const float* __restrict__ wihb, const float* __restrict__ whhb,
                             f16* __restrict__ warr) {
    int i = blockIdx.x * 256 + threadIdx.x;   // 3145728
    int k = i % 768;
    int r = i / 768;                          // (dir*32+wg)*64 + col'
    int colp = r & 63;
    int wg   = (r >> 6) & 31;
    int dir  = r >> 11;
    int gate = colp >> 4, u = colp & 15;
    int row = gate * 512 + wg * 16 + u;
    const float* wih = dir ? wihb : wihf;
    const float* whh = dir ? whhb : whhf;
    float v = (k < 256) ? wih[row * 256 + k] : whh[row * 512 + (k - 256)];
    warr[i] = (f16)v;
}

// ---------------- persistent bidirectional LSTM (per-wave MALL flags) ----------------
// 64 wgs (32/dir), 256 thr. A-frags load directly from global; h + flags via sc1.
// Per-wave flags: producer wave w covers batches [16w,16w+16); consumer wave
// (mh,nh) needs rows [mh*32, mh*32+32) = producer waves {2mh, 2mh+1} of all wgs
// -> its 64 lanes poll exactly those 64 flags. One block barrier per step.
#define GSTR 68   // gate LDS row stride (f32)

__launch_bounds__(THR, 1)
__global__ void k_lstm(const int* __restrict__ tokens,
                       const float* __restrict__ h0, const float* __restrict__ c0,
                       const float* __restrict__ b_f, const float* __restrict__ b_b,
                       const f16* __restrict__ tab, const f16* __restrict__ warr,
                       f16* __restrict__ hbuf, f16* __restrict__ outcat,
                       int* __restrict__ ctl) {
    __shared__ float gate[64 * GSTR];
    __shared__ float cst[64 * 16];

    const int tid = threadIdx.x;
    const int dir = blockIdx.x >> 5, wg = blockIdx.x & 31;

    const int l = tid & 63, w = tid >> 6;
    const int mh = w >> 1, nh = w & 1;
    const int r0 = mh * 32 + (l & 15), r1 = r0 + 16;   // A rows (batch)
    const int kofs = (l >> 4) * 8;                     // lane's k sub-offset (f16)

    // flag pointers: mine (store) and my 64 polled producers (load)
    int* myflag = ctl + 64 + ((dir * 32 + wg) * 4 + w) * 16;
    const int* pollp = ctl + 64 + ((dir * 32 + (l >> 1)) * 4 + mh * 2 + (l & 1)) * 16;

    // ---- preload weights into registers (B fragments) ----
    f16x8 bf0[24], bf1[24];
#pragma unroll
    for (int kt = 0; kt < 24; ++kt) {
        int colp0 = nh * 32 + 0 * 16 + (l & 15);
        int colp1 = nh * 32 + 1 * 16 + (l & 15);
        long base = (long)((dir * 32 + wg) * 64) * 768;
        bf0[kt] = *(const f16x8*)(warr + base + (long)colp0 * 768 + kt * 32 + kofs);
        bf1[kt] = *(const f16x8*)(warr + base + (long)colp1 * 768 + kt * 32 + kofs);
    }

    // ---- epilogue mapping: thread owns (pb, u0..u0+3); wave w owns pb in [16w,16w+16) ----
    const int pb = tid >> 2;
    const int u0 = (tid & 3) * 4;
    const float* bv = dir ? b_b : b_f;
    f32x4 bias[4];
#pragma unroll
    for (int g = 0; g < 4; ++g)
        bias[g] = *(const f32x4*)(bv + g * 512 + wg * 16 + u0);

    // ---- init c (LDS f32) and h (hbuf parity 0, sc1) ----
    {
        f32x4 cv = *(const f32x4*)(c0 + (dir * 64 + pb) * 512 + wg * 16 + u0);
        *(f32x4*)(cst + pb * 16 + u0) = cv;
        f32x4 h4 = *(const f32x4*)(h0 + (dir * 64 + pb) * 512 + wg * 16 + u0);
        f16x4 hv;
#pragma unroll
        for (int j = 0; j < 4; ++j) hv[j] = (f16)h4[j];
        store_f16x4_sc1(hbuf + ((0 * 2 + dir) * 64 + pb) * 512 + wg * 16 + u0, hv);
    }
    drain_vm();                          // wave's h0 slice acked at MALL
    if ((tid & 63) == 0) store_int_sc1(myflag, 1);
    __syncthreads();

    // tokens for step 0
    int tok0 = tokens[(dir ? 511 : 0) * 64 + r0];
    int tok1 = tokens[(dir ? 511 : 0) * 64 + r1];

#pragma unroll 1
    for (int s = 0; s < 512; ++s) {
        const int t_act = dir ? (511 - s) : s;

        // ---- issue emb A-frag loads (latency hides under the poll) ----
        f16x8 e0[8], e1[8];
        {
            const f16* p0 = tab + tok0 * 256 + kofs;
            const f16* p1 = tab + tok1 * 256 + kofs;
            LD4(e0[0], p0, 0);   LD4(e1[0], p1, 0);
            LD4(e0[1], p0, 64);  LD4(e1[1], p1, 64);
            LD4(e0[2], p0, 128); LD4(e1[2], p1, 128);
            LD4(e0[3], p0, 192); LD4(e1[3], p1, 192);
            LD4(e0[4], p0, 256); LD4(e1[4], p1, 256);
            LD4(e0[5], p0, 320); LD4(e1[5], p1, 320);
            LD4(e0[6], p0, 384); LD4(e1[6], p1, 384);
            LD4(e0[7], p0, 448); LD4(e1[7], p1, 448);
        }

        // ---- per-wave poll: the 64 producer-wave flags this wave consumes ----
        {
            const int target = s + 1;
            int guard = 0;
            while (true) {
                int v = load_int_sc1(pollp);   // vmcnt(0) inside also retires emb
                if (__all(v >= target)) break;
                __builtin_amdgcn_s_sleep(1);   // backoff: cut MALL contention
                if (++guard > 4096) break;     // bounded: fail fast, never hang
            }
        }
        __builtin_amdgcn_sched_barrier(0);

        // ---- issue first-half h A-frags (k-tiles 8..15) from MALL ----
        const f16* hbase = hbuf + (long)(((s & 1) * 2 + dir) * 64) * 512;
        const f16* pr0 = hbase + r0 * 512 + kofs;
        const f16* pr1 = hbase + r1 * 512 + kofs;
        f16x8 ha0[8], ha1[8], hc0[8], hc1[8];
        LD4S(ha0[0], pr0, 0);   LD4S(ha1[0], pr1, 0);
        LD4S(ha0[1], pr0, 64);  LD4S(ha1[1], pr1, 64);
        LD4S(ha0[2], pr0, 128); LD4S(ha1[2], pr1, 128);
        LD4S(ha0[3], pr0, 192); LD4S(ha1[3], pr1, 192);
        LD4S(ha0[4], pr0, 256); LD4S(ha1[4], pr1, 256);
        LD4S(ha0[5], pr0, 320); LD4S(ha1[5], pr1, 320);
        LD4S(ha0[6], pr0, 384); LD4S(ha1[6], pr1, 384);
        LD4S(ha0[7], pr0, 448); LD4S(ha1[7], pr1, 448);

        // ---- emb MFMAs (k-tiles 0..7); emb retired by poll's vmcnt(0) ----
        f32x4 a00 = {0.f,0.f,0.f,0.f}, a01 = {0.f,0.f,0.f,0.f};
        f32x4 a10 = {0.f,0.f,0.f,0.f}, a11 = {0.f,0.f,0.f,0.f};
#pragma unroll
        for (int kt = 0; kt < 8; ++kt) {
            a00 = __builtin_amdgcn_mfma_f32_16x16x32_f16(e0[kt], bf0[kt], a00, 0, 0, 0);
            a01 = __builtin_amdgcn_mfma_f32_16x16x32_f16(e0[kt], bf1[kt], a01, 0, 0, 0);
            a10 = __builtin_amdgcn_mfma_f32_16x16x32_f16(e1[kt], bf0[kt], a10, 0, 0, 0);
            a11 = __builtin_amdgcn_mfma_f32_16x16x32_f16(e1[kt], bf1[kt], a11, 0, 0, 0);
        }

        // ---- issue second-half h A-frags (k-tiles 16..23) ----
        LD4S(hc0[0], pr0, 512); LD4S(hc1[0], pr1, 512);
        LD4S(hc0[1], pr0, 576); LD4S(hc1[1], pr1, 576);
        LD4S(hc0[2], pr0, 640); LD4S(hc1[2], pr1, 640);
        LD4S(hc0[3], pr0, 704); LD4S(hc1[3], pr1, 704);
        LD4S(hc0[4], pr0, 768); LD4S(hc1[4], pr1, 768);
        LD4S(hc0[5], pr0, 832); LD4S(hc1[5], pr1, 832);
        LD4S(hc0[6], pr0, 896); LD4S(hc1[6], pr1, 896);
        LD4S(hc0[7], pr0, 960); LD4S(hc1[7], pr1, 960);

        WAITVM(16);   // first-half h frags retired (second half is newest 16)
#pragma unroll
        for (int kt = 0; kt < 8; ++kt) {
            a00 = __builtin_amdgcn_mfma_f32_16x16x32_f16(ha0[kt], bf0[kt + 8], a00, 0, 0, 0);
            a01 = __builtin_amdgcn_mfma_f32_16x16x32_f16(ha0[kt], bf1[kt + 8], a01, 0, 0, 0);
            a10 = __builtin_amdgcn_mfma_f32_16x16x32_f16(ha1[kt], bf0[kt + 8], a10, 0, 0, 0);
            a11 = __builtin_amdgcn_mfma_f32_16x16x32_f16(ha1[kt], bf1[kt + 8], a11, 0, 0, 0);
        }
        WAITVM(0);    // second-half h frags retired
#pragma unroll
        for (int kt = 0; kt < 8; ++kt) {
            a00 = __builtin_amdgcn_mfma_f32_16x16x32_f16(hc0[kt], bf0[kt + 16], a00, 0, 0, 0);
            a01 = __builtin_amdgcn_mfma_f32_16x16x32_f16(hc0[kt], bf1[kt + 16], a01, 0, 0, 0);
            a10 = __builtin_amdgcn_mfma_f32_16x16x32_f16(hc1[kt], bf0[kt + 16], a10, 0, 0, 0);
            a11 = __builtin_amdgcn_mfma_f32_16x16x32_f16(hc1[kt], bf1[kt + 16], a11, 0, 0, 0);
        }

        // ---- write gates to LDS ----
#pragma unroll
        for (int q = 0; q < 4; ++q) {
            int br0 = mh * 32 + (l >> 4) * 4 + q;
            int br1 = br0 + 16;
            int cl0 = nh * 32 + (l & 15);
            gate[br0 * GSTR + cl0]      = a00[q];
            gate[br0 * GSTR + cl0 + 16] = a01[q];
            gate[br1 * GSTR + cl0]      = a10[q];
            gate[br1 * GSTR + cl0 + 16] = a11[q];
        }
        __syncthreads();   // the one block barrier per step (gate exchange)

        // ---- epilogue: tokens for s+1, nonlinearity, c/h update ----
        {
            int sn = (s < 511) ? (s + 1) : 511;
            int tn = dir ? (511 - sn) : sn;
            tok0 = tokens[tn * 64 + r0];
            tok1 = tokens[tn * 64 + r1];
        }
        f16x4 hv;
        {
            f32x4 g0 = *(const f32x4*)(gate + pb * GSTR +  0 + u0);
            f32x4 g1 = *(const f32x4*)(gate + pb * GSTR + 16 + u0);
            f32x4 g2 = *(const f32x4*)(gate + pb * GSTR + 32 + u0);
            f32x4 g3 = *(const f32x4*)(gate + pb * GSTR + 48 + u0);
            f32x4 cv = *(const f32x4*)(cst + pb * 16 + u0);
#pragma unroll
            for (int j = 0; j < 4; ++j) {
                float si = fast_sigmoid(g0[j] + bias[0][j]);
                float sf = fast_sigmoid(g1[j] + bias[1][j]);
                float tg = fast_tanh(g2[j] + bias[2][j]);
                float so = fast_sigmoid(g3[j] + bias[3][j]);
                float c = sf * cv[j] + si * tg;
                float h = so * fast_tanh(c);
                cv[j] = c;
                hv[j] = (f16)h;
            }
            *(f32x4*)(cst + pb * 16 + u0) = cv;
            // h store (sc1 -> MALL); gates this wave's flag
            store_f16x4_sc1(hbuf + ((((s + 1) & 1) * 2 + dir) * 64 + pb) * 512 + wg * 16 + u0, hv);
        }
        drain_vm();                 // this wave's h slice acked at MALL
        if ((tid & 63) == 0) store_int_sc1(myflag, s + 2);
        // outcat store AFTER flag release: off the critical path (L2 ack only)
        *(f16x4*)(outcat + ((long)t_act * 64 + pb) * 1024 + dir * 512 + wg * 16 + u0) = hv;
    }
}

// ---------------- attention GEMM: scores += tanh(out@W_W + b) . w_proj ----------------
__global__ void k_attn_gemm(const f16* __restrict__ outcat, const f16* __restrict__ wwt,
                            const float* __restrict__ b_att, const float* __restrict__ w_proj,
                            float* __restrict__ scores) {
    __shared__ __align__(16) f16 A2[64][136];
    __shared__ __align__(16) f16 B2[64][136];
    __shared__ float sq[64][68];
    const int tid = threadIdx.x;
    const int mb = blockIdx.x >> 4, nb = blockIdx.x & 15;
    const int r0 = mb * 64, c0 = nb * 64;
    const int l = tid & 63, w = tid >> 6;
    const int mh = w >> 1, nhf = w & 1;

    f32x4 acc[2][2];
#pragma unroll
    for (int m = 0; m < 2; ++m)
#pragma unroll
        for (int n = 0; n < 2; ++n)
            acc[m][n] = (f32x4){0.f, 0.f, 0.f, 0.f};

    for (int kc = 0; kc < 8; ++kc) {
        int k0 = kc * 128;
        {
            int row = tid >> 2, seg = tid & 3;
            const f16* sa = outcat + (long)(r0 + row) * 1024 + k0 + seg * 32;
            const f16* sb = wwt + (long)(c0 + row) * 1024 + k0 + seg * 32;
#pragma unroll
            for (int j = 0; j < 4; ++j) {
                *(f16x8*)(&A2[row][seg * 32 + j * 8]) = *(const f16x8*)(sa + j * 8);
                *(f16x8*)(&B2[row][seg * 32 + j * 8]) = *(const f16x8*)(sb + j * 8);
            }
        }
        __syncthreads();
        const int kofs = (l >> 4) * 8;
#pragma unroll
        for (int kt = 0; kt < 4; ++kt) {
            int ko = kt * 32 + kofs;
            f16x8 a0 = *(const f16x8*)(&A2[mh * 32 + (l & 15)][ko]);
            f16x8 a1 = *(const f16x8*)(&A2[mh * 32 + 16 + (l & 15)][ko]);
            f16x8 b0 = *(const f16x8*)(&B2[nhf * 32 + (l & 15)][ko]);
            f16x8 b1 = *(const f16x8*)(&B2[nhf * 32 + 16 + (l & 15)][ko]);
            acc[0][0] = __builtin_amdgcn_mfma_f32_16x16x32_f16(a0, b0, acc[0][0], 0, 0, 0);
            acc[0][1] = __builtin_amdgcn_mfma_f32_16x16x32_f16(a0, b1, acc[0][1], 0, 0, 0);
            acc[1][0] = __builtin_amdgcn_mfma_f32_16x16x32_f16(a1, b0, acc[1][0], 0, 0, 0);
            acc[1][1] = __builtin_amdgcn_mfma_f32_16x16x32_f16(a1, b1, acc[1][1], 0, 0, 0);
        }
        __syncthreads();
    }
#pragma unroll
    for (int m = 0; m < 2; ++m)
#pragma unroll
        for (int n = 0; n < 2; ++n)
#pragma unroll
            for (int q = 0; q < 4; ++q) {
                int rl = mh * 32 + m * 16 + (l >> 4) * 4 + q;
                int cl = nhf * 32 + n * 16 + (l & 15);
                int cg = c0 + cl;
                sq[rl][cl] = tanhf(acc[m][n][q] + b_att[cg]) * w_proj[cg];
            }
    __syncthreads();
    if (tid < 64) {
        float s = 0.f;
#pragma unroll
        for (int c2 = 0; c2 < 64; ++c2) s += sq[tid][c2];
        atomicAdd(scores + r0 + tid, s);
    }
}

// ---------------- softmax over T (per batch) ----------------
__global__ void k_softmax(const float* __restrict__ scores, float* __restrict__ attn) {
    const int b = blockIdx.x, tid = threadIdx.x;
    __shared__ float redm[4];
    __shared__ float reds[4];
    float v0 = scores[(tid * 2 + 0) * 64 + b];
    float v1 = scores[(tid * 2 + 1) * 64 + b];
    float m = fmaxf(v0, v1);
#pragma unroll
    for (int off = 32; off; off >>= 1) m = fmaxf(m, __shfl_down(m, off));
    if ((tid & 63) == 0) redm[tid >> 6] = m;
    __syncthreads();
    m = fmaxf(fmaxf(redm[0], redm[1]), fmaxf(redm[2], redm[3]));
    float e0 = __expf(v0 - m), e1 = __expf(v1 - m);
    float s = e0 + e1;
#pragma unroll
    for (int off = 32; off; off >>= 1) s += __shfl_down(s, off);
    if ((tid & 63) == 0) reds[tid >> 6] = s;
    __syncthreads();
    s = (reds[0] + reds[1]) + (reds[2] + reds[3]);
    float inv = 1.f / s;
    attn[(tid * 2 + 0) * 64 + b] = e0 * inv;
    attn[(tid * 2 + 1) * 64 + b] = e1 * inv;
}

// ---------------- weighted sum: char_vectors[b][c] ----------------
__global__ void k_wsum(const float* __restrict__ attn, const f16* __restrict__ outcat,
                       float* __restrict__ out) {
    const int b = blockIdx.x, tid = threadIdx.x;
    float a0 = 0.f, a1 = 0.f, a2 = 0.f, a3 = 0.f;
    for (int t = 0; t < 512; ++t) {
        float at = attn[t * 64 + b];
        f16x4 v = *(const f16x4*)(outcat + ((long)t * 64 + b) * 1024 + tid * 4);
        a0 += at * (float)v[0];
        a1 += at * (float)v[1];
        a2 += at * (float)v[2];
        a3 += at * (float)v[3];
    }
    float* dst = out + b * 1024 + tid * 4;
    dst[0] = a0; dst[1] = a1; dst[2] = a2; dst[3] = a3;
}

// ---------------- launch ----------------
extern "C" void kernel_launch(void* const* d_in, const int* in_sizes, int n_in,
                              void* d_out, int out_size, void* d_ws, size_t ws_size,
                              hipStream_t stream) {
    if (ws_size < WS_END) return;

    const int*   tokens = (const int*)d_in[0];
    const float* h0     = (const float*)d_in[1];
    const float* c0     = (const float*)d_in[2];
    const float* etab   = (const float*)d_in[3];
    const float* wihf   = (const float*)d_in[4];
    const float* whhf   = (const float*)d_in[5];
    const float* b_f    = (const float*)d_in[6];
    const float* wihb   = (const float*)d_in[7];
    const float* whhb   = (const float*)d_in[8];
    const float* b_b    = (const float*)d_in[9];
    const float* ww     = (const float*)d_in[10];
    const float* b_att  = (const float*)d_in[11];
    const float* w_proj = (const float*)d_in[12];
    float* out = (float*)d_out;

    char* ws = (char*)d_ws;
    int*   ctl    = (int*)(ws + WS_CTL);
    float* scores = (float*)(ws + WS_SCORES);
    float* attn   = (float*)(ws + WS_ATTN);
    f16*   tab    = (f16*)(ws + WS_TAB);
    f16*   warr   = (f16*)(ws + WS_WARR);
    f16*   wwt    = (f16*)(ws + WS_WWT);
    f16*   hbuf   = (f16*)(ws + WS_HBUF);
    f16*   outcat = (f16*)(ws + WS_OUT);

    hipMemsetAsync(d_ws, 0, WS_ZERO_END, stream);

    k_setup_table<<<256, 256, 0, stream>>>(etab, tab);
    k_setup_wwt<<<4096, 256, 0, stream>>>(ww, wwt);
    k_setup_warr<<<12288, 256, 0, stream>>>(wihf, whhf, wihb, whhb, warr);

    k_lstm<<<64, THR, 0, stream>>>(tokens, h0, c0, b_f, b_b,
                                   tab, warr, hbuf, outcat, ctl);

    k_attn_gemm<<<8192, 256, 0, stream>>>(outcat, wwt, b_att, w_proj, scores);
    k_softmax<<<64, 256, 0, stream>>>(scores, attn);
    k_wsum<<<64, 256, 0, stream>>>(attn, outcat, out);
}